// Round 5
// baseline (136.456 us; speedup 1.0000x reference)
//
#include <hip/hip_runtime.h>

#define N 128
#define DIM 8192
#define NN (N * N)      // 16384
#define ZSPLIT 64
#define NW 16           // waves in solve block
#define TCAP 512        // per-wave LDS cost-tile capacity (floats)

// ---------------- wave-sync helpers ----------------------------------------
__device__ __forceinline__ void wave_fence() {
    __threadfence_block();
    __builtin_amdgcn_wave_barrier();
}
__device__ __forceinline__ double embed_key(double v, int j) {
    long long b = __double_as_longlong(v);
    return __longlong_as_double((b & ~127LL) | (long long)j);
}

// ---------------- Stage 1: d2 partials (split-K, no atomics) ----------------
// grid (4,4,64): 32x32 tile, K-chunk 128. 2x2 register tile per thread.
// Partials stored plain to d2p[z][16384]; reduced in solve_kernel prologue.
__global__ __launch_bounds__(256) void d2_partial(const float* __restrict__ A,
                                                  const float* __restrict__ B,
                                                  float* __restrict__ d2p) {
    __shared__ float As[32][68];
    __shared__ float Bk[64][36];   // [k][col], stride 36: write alias 2-way (free)
    const int tid = threadIdx.x;
    const int bi = blockIdx.x, bj = blockIdx.y, bz = blockIdx.z;
    const int tx = tid & 15, ty = tid >> 4;
    const int row0 = bi * 32, col0 = bj * 32;
    const int kbase = bz * 128;
    float a00 = 0.f, a01 = 0.f, a10 = 0.f, a11 = 0.f;

    for (int it = 0; it < 2; ++it) {
        const int k0 = kbase + it * 64;
        __syncthreads();
        #pragma unroll
        for (int s = 0; s < 2; ++s) {          // A: 32 rows x 16 float4
            int e = tid + s * 256;
            int r = e >> 4, q = e & 15;
            *(float4*)&As[r][q * 4] = *(const float4*)&A[(row0 + r) * DIM + k0 + q * 4];
        }
        #pragma unroll
        for (int s = 0; s < 2; ++s) {          // B: k-major transpose store
            int r = tid & 31;
            int kq = (tid >> 5) + s * 8;
            float4 b4 = *(const float4*)&B[(col0 + r) * DIM + k0 + kq * 4];
            Bk[kq * 4 + 0][r] = b4.x;
            Bk[kq * 4 + 1][r] = b4.y;
            Bk[kq * 4 + 2][r] = b4.z;
            Bk[kq * 4 + 3][r] = b4.w;
        }
        __syncthreads();
        #pragma unroll
        for (int kk = 0; kk < 64; kk += 4) {
            float x0[4], x1[4];
            *(float4*)x0 = *(const float4*)&As[2 * ty][kk];
            *(float4*)x1 = *(const float4*)&As[2 * ty + 1][kk];
            float y[4][2];
            #pragma unroll
            for (int q = 0; q < 4; ++q)
                *(float2*)y[q] = *(const float2*)&Bk[kk + q][2 * tx];
            #pragma unroll
            for (int q = 0; q < 4; ++q) {
                float d;
                d = x0[q] - y[q][0]; a00 = fmaf(d, d, a00);
                d = x0[q] - y[q][1]; a01 = fmaf(d, d, a01);
                d = x1[q] - y[q][0]; a10 = fmaf(d, d, a10);
                d = x1[q] - y[q][1]; a11 = fmaf(d, d, a11);
            }
        }
    }
    const int o0 = (row0 + 2 * ty) * N + col0 + 2 * tx;
    float* dst = d2p + bz * NN;
    *(float2*)&dst[o0]     = make_float2(a00, a01);
    *(float2*)&dst[o0 + N] = make_float2(a10, a11);
}

// ---------------- Stage 2: reduce + decompose + per-class Hungarian ---------
__global__ __launch_bounds__(1024) void solve_kernel(const float* __restrict__ d2p,
                                                     float* __restrict__ gmt,
                                                     const int* __restrict__ t1,
                                                     const int* __restrict__ t2,
                                                     float* __restrict__ out) {
    __shared__ int lbl1[N], lbl2[N];
    __shared__ int rowlist[N], collist[N];
    __shared__ int rcnt[64], ccnt[64], rstart[65], cstart[65], rcur[64], ccur[64];
    __shared__ int tasks[65], bigtasks[65];
    __shared__ int ntasks_s, nbig_s, flag_s;
    __shared__ double totals[NW];
    __shared__ float ctile[NW][TCAP];
    __shared__ int   claimw[NW][64];
    // block-wide (fallback) solver scratch
    __shared__ double ub[N + 1], vbp[N + 1], minvb[N + 1];
    __shared__ int pb[N + 1], wayb[N + 1], usedb[N + 1];
    __shared__ double redv[NW];
    __shared__ int redi[NW];
    __shared__ double big_total;
    __shared__ int jfin_s;

    const int tid = threadIdx.x;
    if (tid < 64) { rcnt[tid] = 0; ccnt[tid] = 0; rcur[tid] = 0; ccur[tid] = 0; }
    if (tid == 0) { ntasks_s = 0; nbig_s = 0; flag_s = 0; big_total = 0.0; }
    if (tid < N)  { lbl1[tid] = t1[tid]; lbl2[tid] = t2[tid]; }
    __syncthreads();
    if (tid < N) {
        int l1 = lbl1[tid], l2 = lbl2[tid];
        if (l1 < 0 || l1 > 63 || l2 < 0 || l2 > 63) atomicOr(&flag_s, 1);
        atomicAdd(&rcnt[l1 & 63], 1);
        atomicAdd(&ccnt[l2 & 63], 1);
    }
    // ---- reduce z-partials, transform -> gm, store, detect cross-label >0 ----
    {
        float accp[16];
        #pragma unroll
        for (int p = 0; p < 16; ++p) accp[p] = 0.f;
        for (int z = 0; z < ZSPLIT; ++z) {
            const float* src = d2p + z * NN + tid;
            #pragma unroll
            for (int p = 0; p < 16; ++p) accp[p] += src[p * 1024];
        }
        #pragma unroll
        for (int p = 0; p < 16; ++p) {
            int o = tid + p * 1024;
            int i = o >> 7, j = o & 127;
            bool same = (lbl1[i] == lbl2[j]);
            float g = same ? fmaxf(accp[p], 0.f) : fmaxf(200.f - accp[p], 0.f);
            if (!same && g > 0.f) atomicOr(&flag_s, 1);
            gmt[o] = g;
        }
    }
    __threadfence();
    __syncthreads();
    // wave-0 prefix over class counts + ballot task compaction
    if (tid < 64) {
        int rs_ = rcnt[tid], cs_ = ccnt[tid];
        #pragma unroll
        for (int o = 1; o < 64; o <<= 1) {
            int tr = __shfl_up(rs_, o, 64);
            int tc = __shfl_up(cs_, o, 64);
            if (tid >= o) { rs_ += tr; cs_ += tc; }
        }
        rstart[tid + 1] = rs_;
        cstart[tid + 1] = cs_;
        if (tid == 0) { rstart[0] = 0; cstart[0] = 0; }
        if (!flag_s) {
            int R = rcnt[tid], C = ccnt[tid];
            bool valid = (R > 0) && (C > 0);
            bool small = valid && (R <= 64) && (C <= 64);
            bool big   = valid && !small;
            unsigned long long ms = __ballot(small);
            unsigned long long mb = __ballot(big);
            if (small) tasks[__popcll(ms & ((1ull << tid) - 1))] = tid;
            if (big)   bigtasks[__popcll(mb & ((1ull << tid) - 1))] = tid;
            if (tid == 0) { ntasks_s = __popcll(ms); nbig_s = __popcll(mb); }
        } else if (tid == 0) { ntasks_s = 0; nbig_s = 1; bigtasks[0] = -1; }
    }
    __syncthreads();
    if (tid < N) {       // counting-sort scatter
        int l1 = lbl1[tid] & 63;
        int p = atomicAdd(&rcur[l1], 1);
        rowlist[rstart[l1] + p] = tid;
        int l2 = lbl2[tid] & 63;
        int q = atomicAdd(&ccur[l2], 1);
        collist[cstart[l2] + q] = tid;
    }
    __syncthreads();

    const int w = tid >> 6, lane = tid & 63;
    const int ntasks = ntasks_s;
    double acc = 0.0;

    // ================= lean wave solver (single-role lanes) =================
    for (int tk = w; tk < ntasks; tk += NW) {
        const int c = tasks[tk];
        const int Rn = rcnt[c], Cn = ccnt[c];
        const int* rl = rowlist + rstart[c];
        const int* cl = collist + cstart[c];
        const bool T  = (Rn > Cn);
        const int n_  = T ? Cn : Rn;
        const int m_  = T ? Rn : Cn;        // n_ <= m_ <= 64
        const bool tl = (n_ * m_ <= TCAP);
        float* Cw = ctile[w];
        int*  clm = claimw[w];

        auto offg = [&](int j) { return T ? rl[j] * N : cl[j]; };
        auto rbg  = [&](int i) { return T ? cl[i] : rl[i] * N; };

        if (tl) {
            for (int e = lane; e < n_ * m_; e += 64) {
                int i = e / m_, j = e - i * m_;
                Cw[e] = gmt[rbg(i) + offg(j)];
            }
        }
        wave_fence();

        const float* CM = tl ? Cw : gmt;
        const bool cA = (lane < m_), rA = (lane < n_);
        const int myoff = cA ? (tl ? lane : offg(lane)) : 0;     // col role
        const int myrb  = rA ? (tl ? lane * m_ : rbg(lane)) : 0; // row role

        // row reduction: u = -max_j gm(row=lane, j)
        double u = 0.0;
        if (rA) {
            float mx = 0.f;
            for (int j = 0; j < m_; ++j) mx = fmaxf(mx, CM[myrb + (tl ? j : offg(j))]);
            u = -(double)mx;
        }
        // col reduction: v = min_i (-gm(i, col=lane) - u_i)
        double v = 1e30;
        for (int i = 0; i < n_; ++i) {
            double ui = __shfl(u, i, 64);
            int rb = tl ? i * m_ : rbg(i);
            if (cA) v = fmin(v, -(double)CM[rb + myoff] - ui);
        }
        // greedy tight assignment
        if (cA) clm[lane] = 0x7fffffff;
        wave_fence();
        int jc = -1;
        for (int j = 0; j < m_; ++j) {
            double vj = __shfl(v, j, 64);
            int ofj = tl ? j : offg(j);
            if (rA && jc < 0) {
                double s = -(double)CM[myrb + ofj] - u - vj;
                if (s < 1e-7) jc = j;
            }
        }
        if (rA && jc >= 0) atomicMin(&clm[jc], lane);
        wave_fence();
        int p = -1;                           // col role: matched row
        if (cA && clm[lane] != 0x7fffffff) p = clm[lane];
        bool rowm = (rA && jc >= 0 && clm[jc] == lane);

        // augmentation phases
        for (int ir = 0; ir < n_; ++ir) {
            if (__shfl(rowm ? 1 : 0, ir, 64)) continue;
            double minv = 1e30, markD = -1.0, ent = -1.0;
            bool used = false; int way = -2;
            if (rA && lane == ir) ent = 0.0;
            double D = 0.0;
            int i0 = ir, jprev = -1;
            int guard = 2 * m_ + 8;
            while (guard-- > 0) {
                double ui = __shfl(u, i0, 64);
                int rb = tl ? i0 * m_ : rbg(i0);
                if (cA && !used) {
                    double cand = D - ui - (double)CM[rb + myoff] - v;
                    if (cand < minv) { minv = cand; way = jprev; }
                }
                double kd = (cA && !used) ? embed_key(minv, lane) : 1e30;
                #pragma unroll
                for (int o = 1; o < 64; o <<= 1) kd = fmin(kd, __shfl_xor(kd, o, 64));
                long long kb = __double_as_longlong(kd);
                int j1 = (int)(kb & 127);
                double Dn = __longlong_as_double(kb & ~127LL);
                if (Dn > 1e29) break;
                D = Dn;
                int i1 = __shfl(p, j1, 64);
                if (i1 < 0) {                 // free col: augment along way[]
                    int jj = j1;
                    while (true) {
                        int wp = __shfl(way, jj, 64);
                        int pn = (wp < 0) ? ir : __shfl(p, wp, 64);
                        if (cA && lane == jj) p = pn;
                        if (wp < 0) break;
                        jj = wp;
                    }
                    if (rA && lane == ir) rowm = true;
                    break;
                }
                if (cA && lane == j1) { used = true; markD = D; }
                if (rA && lane == i1) ent = D;
                jprev = j1; i0 = i1;
            }
            if (rA && ent   >= 0.0) u += D - ent;
            if (cA && markD >= 0.0) v -= D - markD;
        }

        // class value
        double val = 0.0;
        if (cA && p >= 0) {
            int rb = tl ? p * m_ : rbg(p);
            val = (double)CM[rb + myoff];
        }
        #pragma unroll
        for (int o = 1; o < 64; o <<= 1) val += __shfl_xor(val, o, 64);
        acc += val;
    }
    if (lane == 0) totals[w] = acc;
    __syncthreads();

    // ================= block-wide fallback solver (rare) ====================
    const int nbig = nbig_s;
    for (int bt = 0; bt < nbig; ++bt) {
        const int c = bigtasks[bt];
        int Rn, Cn, rs, cs;
        if (c < 0) { Rn = N; Cn = N; rs = 0; cs = 0; }
        else { Rn = rcnt[c]; Cn = ccnt[c]; rs = rstart[c]; cs = cstart[c]; }
        const bool T = (Rn > Cn);
        const int n_ = T ? Cn : Rn, m_ = T ? Rn : Cn;
        auto cost = [&](int i, int j) -> double {   // oriented 0-based
            int oi = (c < 0) ? i : (T ? collist[cs + i] : rowlist[rs + i]);
            int oj = (c < 0) ? j : (T ? rowlist[rs + j] : collist[cs + j]);
            int rr = T ? oj : oi, cc2 = T ? oi : oj;
            return -(double)gmt[rr * N + cc2];
        };
        for (int x = tid; x <= m_; x += 1024) { vbp[x] = 0.0; pb[x] = 0; }
        for (int x = tid; x <= n_; x += 1024) { ub[x] = 0.0; }
        __syncthreads();
        for (int i = 1; i <= n_; ++i) {
            if (tid == 0) pb[0] = i;
            for (int x = tid; x <= m_; x += 1024) { minvb[x] = 1e300; usedb[x] = 0; }
            __syncthreads();
            int j0 = 0;
            int guard = 2 * m_ + 8;
            while (guard-- > 0) {
                if (tid == 0) usedb[j0] = 1;
                __syncthreads();
                const int i0 = pb[j0];
                double dl = 1e300; int jl = 0;
                if (tid < m_) {
                    int j = tid + 1;
                    if (!usedb[j]) {
                        double cur = cost(i0 - 1, j - 1) - ub[i0] - vbp[j];
                        if (cur < minvb[j]) { minvb[j] = cur; wayb[j] = j0; }
                        dl = minvb[j]; jl = j;
                    }
                }
                double rv = dl; int ri = jl;
                #pragma unroll
                for (int o = 32; o > 0; o >>= 1) {
                    double ov = __shfl_down(rv, o, 64);
                    int oi2 = __shfl_down(ri, o, 64);
                    if (ov < rv) { rv = ov; ri = oi2; }
                }
                if ((tid & 63) == 0) { redv[tid >> 6] = rv; redi[tid >> 6] = ri; }
                __syncthreads();
                if (tid == 0) {
                    double bd = 1e300; int bj = 0;
                    for (int q = 0; q < NW; ++q) if (redv[q] < bd) { bd = redv[q]; bj = redi[q]; }
                    redv[0] = bd; redi[0] = bj;
                }
                __syncthreads();
                const double delta = redv[0];
                const int j1 = redi[0];
                if (tid < m_) {
                    int j = tid + 1;
                    if (usedb[j]) { ub[pb[j]] += delta; vbp[j] -= delta; }
                    else          { minvb[j] -= delta; }
                }
                if (tid == 0) ub[pb[0]] += delta;
                __syncthreads();
                j0 = j1;
                if (pb[j0] == 0) break;
            }
            if (tid == 0) jfin_s = j0;
            __syncthreads();
            if (tid == 0) {
                int jj = jfin_s;
                while (jj) { int jp = wayb[jj]; pb[jj] = pb[jp]; jj = jp; }
            }
            __syncthreads();
        }
        double bl = 0.0;
        if (tid < m_) { int j = tid + 1; if (pb[j] != 0) bl = -cost(pb[j] - 1, j - 1); }
        #pragma unroll
        for (int o = 32; o > 0; o >>= 1) bl += __shfl_down(bl, o, 64);
        if ((tid & 63) == 0) redv[tid >> 6] = bl;
        __syncthreads();
        if (tid == 0) { double s = 0; for (int q = 0; q < NW; ++q) s += redv[q]; big_total += s; }
        __syncthreads();
    }

    if (tid == 0) {
        double s = big_total;
        for (int i = 0; i < NW; ++i) s += totals[i];
        out[0] = (float)(s / (double)N);
    }
}

extern "C" void kernel_launch(void* const* d_in, const int* in_sizes, int n_in,
                              void* d_out, int out_size, void* d_ws, size_t ws_size,
                              hipStream_t stream) {
    const float* A  = (const float*)d_in[0];
    const float* B  = (const float*)d_in[1];
    const int*   t1 = (const int*)d_in[2];
    const int*   t2 = (const int*)d_in[3];
    float* out = (float*)d_out;
    float* d2p = (float*)d_ws;                       // [64][16384] partials, 4 MB
    float* gmt = (float*)d_ws + ZSPLIT * NN;         // [128][128] gm, 64 KB

    d2_partial<<<dim3(4, 4, ZSPLIT), 256, 0, stream>>>(A, B, d2p);
    solve_kernel<<<1, 1024, 0, stream>>>(d2p, gmt, t1, t2, out);
}

// Round 6
// 90.607 us; speedup vs baseline: 1.5060x; 1.5060x over previous
//
#include <hip/hip_runtime.h>

#define N 128
#define DIM 8192
#define NN (N * N)      // 16384
#define ZSPLIT 64
#define NW 16           // waves in solve block
#define GSTRIDE 130     // LDS gm row stride: 130%32=2 -> 2-way alias (free)

// ---------------- wave-sync helpers ----------------------------------------
__device__ __forceinline__ void wave_fence() {
    __threadfence_block();
    __builtin_amdgcn_wave_barrier();
}
__device__ __forceinline__ double embed_key(double v, int j) {
    long long b = __double_as_longlong(v);
    return __longlong_as_double((b & ~127LL) | (long long)j);
}

// ---------------- Stage 1: d2 partials (split-K, no atomics) ----------------
// grid (4,4,64): 32x32 tile, K-chunk 128. 2x2 register tile per thread.
__global__ __launch_bounds__(256) void d2_partial(const float* __restrict__ A,
                                                  const float* __restrict__ B,
                                                  float* __restrict__ d2p) {
    __shared__ float As[32][68];
    __shared__ float Bk[64][36];
    const int tid = threadIdx.x;
    const int bi = blockIdx.x, bj = blockIdx.y, bz = blockIdx.z;
    const int tx = tid & 15, ty = tid >> 4;
    const int row0 = bi * 32, col0 = bj * 32;
    const int kbase = bz * 128;
    float a00 = 0.f, a01 = 0.f, a10 = 0.f, a11 = 0.f;

    for (int it = 0; it < 2; ++it) {
        const int k0 = kbase + it * 64;
        __syncthreads();
        #pragma unroll
        for (int s = 0; s < 2; ++s) {
            int e = tid + s * 256;
            int r = e >> 4, q = e & 15;
            *(float4*)&As[r][q * 4] = *(const float4*)&A[(row0 + r) * DIM + k0 + q * 4];
        }
        #pragma unroll
        for (int s = 0; s < 2; ++s) {
            int r = tid & 31;
            int kq = (tid >> 5) + s * 8;
            float4 b4 = *(const float4*)&B[(col0 + r) * DIM + k0 + kq * 4];
            Bk[kq * 4 + 0][r] = b4.x;
            Bk[kq * 4 + 1][r] = b4.y;
            Bk[kq * 4 + 2][r] = b4.z;
            Bk[kq * 4 + 3][r] = b4.w;
        }
        __syncthreads();
        #pragma unroll
        for (int kk = 0; kk < 64; kk += 4) {
            float x0[4], x1[4];
            *(float4*)x0 = *(const float4*)&As[2 * ty][kk];
            *(float4*)x1 = *(const float4*)&As[2 * ty + 1][kk];
            float y[4][2];
            #pragma unroll
            for (int q = 0; q < 4; ++q)
                *(float2*)y[q] = *(const float2*)&Bk[kk + q][2 * tx];
            #pragma unroll
            for (int q = 0; q < 4; ++q) {
                float d;
                d = x0[q] - y[q][0]; a00 = fmaf(d, d, a00);
                d = x0[q] - y[q][1]; a01 = fmaf(d, d, a01);
                d = x1[q] - y[q][0]; a10 = fmaf(d, d, a10);
                d = x1[q] - y[q][1]; a11 = fmaf(d, d, a11);
            }
        }
    }
    const int o0 = (row0 + 2 * ty) * N + col0 + 2 * tx;
    float* dst = d2p + bz * NN;
    *(float2*)&dst[o0]     = make_float2(a00, a01);
    *(float2*)&dst[o0 + N] = make_float2(a10, a11);
}

// ---------------- Stage 1.5: z-reduce + transform -> gm ---------------------
// 64 blocks x 256 threads: one output element per thread, 8-way MLP over z.
__global__ __launch_bounds__(256) void reduce_gm(const float* __restrict__ d2p,
                                                 const int* __restrict__ t1,
                                                 const int* __restrict__ t2,
                                                 float* __restrict__ gm,
                                                 int* __restrict__ flagarr) {
    __shared__ int bf;
    if (threadIdx.x == 0) bf = 0;
    __syncthreads();
    const int o = blockIdx.x * 256 + threadIdx.x;
    float s0 = 0.f, s1 = 0.f, s2 = 0.f, s3 = 0.f, s4 = 0.f, s5 = 0.f, s6 = 0.f, s7 = 0.f;
    const float* p = d2p + o;
    #pragma unroll
    for (int z = 0; z < ZSPLIT; z += 8) {
        s0 += p[(z + 0) * NN]; s1 += p[(z + 1) * NN];
        s2 += p[(z + 2) * NN]; s3 += p[(z + 3) * NN];
        s4 += p[(z + 4) * NN]; s5 += p[(z + 5) * NN];
        s6 += p[(z + 6) * NN]; s7 += p[(z + 7) * NN];
    }
    float s = ((s0 + s1) + (s2 + s3)) + ((s4 + s5) + (s6 + s7));
    const int i = o >> 7, j = o & 127;
    const int l1 = t1[i], l2 = t2[j];
    const bool same = (l1 == l2);
    float g = same ? fmaxf(s, 0.f) : fmaxf(200.f - s, 0.f);
    gm[o] = g;
    bool bad = (!same && g > 0.f) || l1 < 0 || l1 > 63 || l2 < 0 || l2 > 63;
    unsigned long long m = __ballot(bad);
    if ((threadIdx.x & 63) == 0 && m) atomicOr(&bf, 1);
    __syncthreads();
    if (threadIdx.x == 0) flagarr[blockIdx.x] = bf;
}

// ---------------- Stage 2: decompose + per-class Hungarian ------------------
// Single block. gm staged into LDS permuted by class grouping; every class is
// a contiguous LDS submatrix with linear index math. Lean single-role wave
// solver for classes with m<=64; block-wide fallback otherwise (never on the
// expected input).
__global__ __launch_bounds__(1024) void solve_kernel(const float* __restrict__ gm,
                                                     const int* __restrict__ flagarr,
                                                     const int* __restrict__ t1,
                                                     const int* __restrict__ t2,
                                                     float* __restrict__ out) {
    __shared__ float gml[N * GSTRIDE];
    __shared__ int lbl1[N], lbl2[N];
    __shared__ int rowlist[N], collist[N];
    __shared__ int rcnt[64], ccnt[64], rstart[65], cstart[65], rcur[64], ccur[64];
    __shared__ int tasks[65], bigtasks[65];
    __shared__ int ntasks_s, nbig_s, flag_s;
    __shared__ double totals[NW];
    __shared__ int claimw[NW][64];
    // block-wide fallback solver scratch
    __shared__ double ub[N + 1], vbp[N + 1], minvb[N + 1];
    __shared__ int pb[N + 1], wayb[N + 1], usedb[N + 1];
    __shared__ double redv[NW];
    __shared__ int redi[NW];
    __shared__ double big_total;
    __shared__ int jfin_s;

    const int tid = threadIdx.x;
    if (tid < 64) { rcnt[tid] = 0; ccnt[tid] = 0; rcur[tid] = 0; ccur[tid] = 0; }
    if (tid == 0) { ntasks_s = 0; nbig_s = 0; flag_s = 0; big_total = 0.0; }
    if (tid < N)  { lbl1[tid] = t1[tid]; lbl2[tid] = t2[tid]; }
    __syncthreads();
    if (tid < 64 && flagarr[tid]) atomicOr(&flag_s, 1);
    if (tid < N) {
        atomicAdd(&rcnt[lbl1[tid] & 63], 1);
        atomicAdd(&ccnt[lbl2[tid] & 63], 1);
    }
    __syncthreads();
    // wave-0 prefix over class counts + ballot task compaction
    if (tid < 64) {
        int rs_ = rcnt[tid], cs_ = ccnt[tid];
        #pragma unroll
        for (int o = 1; o < 64; o <<= 1) {
            int tr = __shfl_up(rs_, o, 64);
            int tc = __shfl_up(cs_, o, 64);
            if (tid >= o) { rs_ += tr; cs_ += tc; }
        }
        rstart[tid + 1] = rs_;
        cstart[tid + 1] = cs_;
        if (tid == 0) { rstart[0] = 0; cstart[0] = 0; }
        if (!flag_s) {
            int R = rcnt[tid], C = ccnt[tid];
            bool valid = (R > 0) && (C > 0);
            bool small = valid && (R <= 64) && (C <= 64);
            bool big   = valid && !small;
            unsigned long long ms = __ballot(small);
            unsigned long long mb = __ballot(big);
            if (small) tasks[__popcll(ms & ((1ull << tid) - 1))] = tid;
            if (big)   bigtasks[__popcll(mb & ((1ull << tid) - 1))] = tid;
            if (tid == 0) { ntasks_s = __popcll(ms); nbig_s = __popcll(mb); }
        } else if (tid == 0) { ntasks_s = 0; nbig_s = 1; bigtasks[0] = -1; }
    }
    __syncthreads();
    if (tid < N) {       // counting-sort scatter
        int l1 = lbl1[tid] & 63;
        int p = atomicAdd(&rcur[l1], 1);
        rowlist[rstart[l1] + p] = tid;
        int l2 = lbl2[tid] & 63;
        int q = atomicAdd(&ccur[l2], 1);
        collist[cstart[l2] + q] = tid;
    }
    __syncthreads();
    // permuted gm load: class submatrices become contiguous LDS blocks
    #pragma unroll
    for (int pch = 0; pch < 16; ++pch) {
        int e = tid + pch * 1024;
        int i = e >> 7, j = e & 127;
        gml[i * GSTRIDE + j] = gm[rowlist[i] * N + collist[j]];
    }
    __syncthreads();

    const int w = tid >> 6, lane = tid & 63;
    const int ntasks = ntasks_s;
    double acc = 0.0;

    // ================= lean wave solver (single-role lanes) =================
    for (int tk = w; tk < ntasks; tk += NW) {
        const int c = tasks[tk];
        const int Rn = rcnt[c], Cn = ccnt[c], rs = rstart[c], cs = cstart[c];
        const bool T  = (Rn > Cn);
        const int n_  = T ? Cn : Rn;
        const int m_  = T ? Rn : Cn;        // n_ <= m_ <= 64
        const int rstep = T ? 1 : GSTRIDE;
        const int cstep = T ? GSTRIDE : 1;
        const int rb00 = T ? cs : rs * GSTRIDE;   // rb(i) = rb00 + i*rstep
        const int ob00 = T ? rs * GSTRIDE : cs;   // off(j) = ob00 + j*cstep
        int* clm = claimw[w];

        const bool cA = (lane < m_), rA = (lane < n_);
        const int myoff = ob00 + lane * cstep;    // col role
        const int myrb  = rb00 + lane * rstep;    // row role

        // row reduction: u = -max_j gm(row=lane, j)
        double u = 0.0;
        if (rA) {
            float mx = 0.f;
            int a = myrb + ob00;
            for (int j = 0; j < m_; ++j) { mx = fmaxf(mx, gml[a]); a += cstep; }
            u = -(double)mx;
        }
        // col reduction: v = min_i (-gm(i, col=lane) - u_i)
        double v = 1e30;
        {
            int a = rb00 + myoff;
            for (int i = 0; i < n_; ++i) {
                double ui = __shfl(u, i, 64);
                if (cA) v = fmin(v, -(double)gml[a] - ui);
                a += rstep;
            }
        }
        // greedy tight assignment
        if (cA) clm[lane] = 0x7fffffff;
        wave_fence();
        int jc = -1;
        {
            int a = myrb + ob00;
            for (int j = 0; j < m_; ++j) {
                double vj = __shfl(v, j, 64);
                if (rA && jc < 0) {
                    double s = -(double)gml[a] - u - vj;
                    if (s < 1e-7) jc = j;
                }
                a += cstep;
            }
        }
        if (rA && jc >= 0) atomicMin(&clm[jc], lane);
        wave_fence();
        int p = -1;                           // col role: matched row
        if (cA && clm[lane] != 0x7fffffff) p = clm[lane];
        bool rowm = (rA && jc >= 0 && clm[jc] == lane);

        // augmentation phases
        for (int ir = 0; ir < n_; ++ir) {
            if (__shfl(rowm ? 1 : 0, ir, 64)) continue;
            double minv = 1e30, markD = -1.0, ent = -1.0;
            bool used = false; int way = -2;
            if (rA && lane == ir) ent = 0.0;
            double D = 0.0;
            int i0 = ir, jprev = -1;
            int guard = 2 * m_ + 8;
            while (guard-- > 0) {
                double ui = __shfl(u, i0, 64);
                int rb = rb00 + i0 * rstep;
                if (cA && !used) {
                    double cand = D - ui - (double)gml[rb + myoff] - v;
                    if (cand < minv) { minv = cand; way = jprev; }
                }
                double kd = (cA && !used) ? embed_key(minv, lane) : 1e30;
                #pragma unroll
                for (int o = 1; o < 64; o <<= 1) kd = fmin(kd, __shfl_xor(kd, o, 64));
                long long kb = __double_as_longlong(kd);
                int j1 = (int)(kb & 127);
                double Dn = __longlong_as_double(kb & ~127LL);
                if (Dn > 1e29) break;
                D = Dn;
                int i1 = __shfl(p, j1, 64);
                if (i1 < 0) {                 // free col: augment along way[]
                    int jj = j1;
                    while (true) {
                        int wp = __shfl(way, jj, 64);
                        int pn = (wp < 0) ? ir : __shfl(p, wp, 64);
                        if (cA && lane == jj) p = pn;
                        if (wp < 0) break;
                        jj = wp;
                    }
                    if (rA && lane == ir) rowm = true;
                    break;
                }
                if (cA && lane == j1) { used = true; markD = D; }
                if (rA && lane == i1) ent = D;
                jprev = j1; i0 = i1;
            }
            if (rA && ent   >= 0.0) u += D - ent;
            if (cA && markD >= 0.0) v -= D - markD;
        }

        // class value
        double val = 0.0;
        if (cA && p >= 0) val = (double)gml[rb00 + p * rstep + myoff];
        #pragma unroll
        for (int o = 1; o < 64; o <<= 1) val += __shfl_xor(val, o, 64);
        acc += val;
    }
    if (lane == 0) totals[w] = acc;
    __syncthreads();

    // ================= block-wide fallback solver (rare) ====================
    const int nbig = nbig_s;
    for (int bt = 0; bt < nbig; ++bt) {
        const int c = bigtasks[bt];
        int Rn, Cn, rs, cs;
        if (c < 0) { Rn = N; Cn = N; rs = 0; cs = 0; }
        else { Rn = rcnt[c]; Cn = ccnt[c]; rs = rstart[c]; cs = cstart[c]; }
        const bool T = (Rn > Cn);
        const int n_ = T ? Cn : Rn, m_ = T ? Rn : Cn;
        const int rstep = T ? 1 : GSTRIDE;
        const int cstep = T ? GSTRIDE : 1;
        const int rb00 = T ? cs : rs * GSTRIDE;
        const int ob00 = T ? rs * GSTRIDE : cs;
        auto cost = [&](int i, int j) -> double {
            return -(double)gml[rb00 + i * rstep + ob00 + j * cstep];
        };
        for (int x = tid; x <= m_; x += 1024) { vbp[x] = 0.0; pb[x] = 0; }
        for (int x = tid; x <= n_; x += 1024) { ub[x] = 0.0; }
        __syncthreads();
        for (int i = 1; i <= n_; ++i) {
            if (tid == 0) pb[0] = i;
            for (int x = tid; x <= m_; x += 1024) { minvb[x] = 1e300; usedb[x] = 0; }
            __syncthreads();
            int j0 = 0;
            int guard = 2 * m_ + 8;
            while (guard-- > 0) {
                if (tid == 0) usedb[j0] = 1;
                __syncthreads();
                const int i0 = pb[j0];
                double dl = 1e300; int jl = 0;
                if (tid < m_) {
                    int j = tid + 1;
                    if (!usedb[j]) {
                        double cur = cost(i0 - 1, j - 1) - ub[i0] - vbp[j];
                        if (cur < minvb[j]) { minvb[j] = cur; wayb[j] = j0; }
                        dl = minvb[j]; jl = j;
                    }
                }
                double rv = dl; int ri = jl;
                #pragma unroll
                for (int o = 32; o > 0; o >>= 1) {
                    double ov = __shfl_down(rv, o, 64);
                    int oi2 = __shfl_down(ri, o, 64);
                    if (ov < rv) { rv = ov; ri = oi2; }
                }
                if ((tid & 63) == 0) { redv[tid >> 6] = rv; redi[tid >> 6] = ri; }
                __syncthreads();
                if (tid == 0) {
                    double bd = 1e300; int bj = 0;
                    for (int q = 0; q < NW; ++q) if (redv[q] < bd) { bd = redv[q]; bj = redi[q]; }
                    redv[0] = bd; redi[0] = bj;
                }
                __syncthreads();
                const double delta = redv[0];
                const int j1 = redi[0];
                if (tid < m_) {
                    int j = tid + 1;
                    if (usedb[j]) { ub[pb[j]] += delta; vbp[j] -= delta; }
                    else          { minvb[j] -= delta; }
                }
                if (tid == 0) ub[pb[0]] += delta;
                __syncthreads();
                j0 = j1;
                if (pb[j0] == 0) break;
            }
            if (tid == 0) jfin_s = j0;
            __syncthreads();
            if (tid == 0) {
                int jj = jfin_s;
                while (jj) { int jp = wayb[jj]; pb[jj] = pb[jp]; jj = jp; }
            }
            __syncthreads();
        }
        double bl = 0.0;
        if (tid < m_) { int j = tid + 1; if (pb[j] != 0) bl = -cost(pb[j] - 1, j - 1); }
        #pragma unroll
        for (int o = 32; o > 0; o >>= 1) bl += __shfl_down(bl, o, 64);
        if ((tid & 63) == 0) redv[tid >> 6] = bl;
        __syncthreads();
        if (tid == 0) { double s = 0; for (int q = 0; q < NW; ++q) s += redv[q]; big_total += s; }
        __syncthreads();
    }

    if (tid == 0) {
        double s = big_total;
        for (int i = 0; i < NW; ++i) s += totals[i];
        out[0] = (float)(s / (double)N);
    }
}

extern "C" void kernel_launch(void* const* d_in, const int* in_sizes, int n_in,
                              void* d_out, int out_size, void* d_ws, size_t ws_size,
                              hipStream_t stream) {
    const float* A  = (const float*)d_in[0];
    const float* B  = (const float*)d_in[1];
    const int*   t1 = (const int*)d_in[2];
    const int*   t2 = (const int*)d_in[3];
    float* out = (float*)d_out;
    float* d2p = (float*)d_ws;                        // [64][16384] partials, 4 MB
    float* gm  = (float*)d_ws + ZSPLIT * NN;          // [128][128] gm, 64 KB
    int*   flagarr = (int*)(gm + NN);                 // [64] cross-label flags

    d2_partial<<<dim3(4, 4, ZSPLIT), 256, 0, stream>>>(A, B, d2p);
    reduce_gm<<<64, 256, 0, stream>>>(d2p, t1, t2, gm, flagarr);
    solve_kernel<<<1, 1024, 0, stream>>>(gm, flagarr, t1, t2, out);
}